// Round 1
// baseline (164.972 us; speedup 1.0000x reference)
//
#include <hip/hip_runtime.h>

#define NG 76
#define NPOS (NG * NG)            // 5776
#define NC 85                     // 5 + 80
#define NA 3
#define POS_PER_BLOCK 16
#define TILES_PER_PLANE (NPOS / POS_PER_BLOCK)   // 361
#define TILE_ELEMS (POS_PER_BLOCK * NC)          // 1360
#define STRIDE_F 8.0f             // 608 / 76

// exp(w) * scaled_anchor * stride == exp(w) * ANCHOR  (scaled = ANCHOR/stride)
__constant__ float c_aw[NA] = {10.0f, 16.0f, 33.0f};
__constant__ float c_ah[NA] = {13.0f, 30.0f, 23.0f};

__device__ __forceinline__ float fast_sigmoid(float x) {
    return __builtin_amdgcn_rcpf(1.0f + __expf(-x));
}

__global__ __launch_bounds__(256) void det_kernel(const float* __restrict__ in,
                                                  float* __restrict__ out) {
    // LDS holds the tile already transposed to output order: index = p*NC + c
    __shared__ float lds[TILE_ELEMS];

    const int bid   = blockIdx.x;
    const int plane = bid / TILES_PER_PLANE;          // b*NA + a
    const int tile  = bid - plane * TILES_PER_PLANE;
    const int a     = plane % NA;
    const int pos0  = tile * POS_PER_BLOCK;
    const int t     = threadIdx.x;

    const float* in_plane = in + (size_t)plane * (NC * NPOS) + pos0;

    // ---- load phase: 85 channels x 4 float4-vectors (16 positions) ----
    // v -> c = v>>2, pq = v&3; read 4 consecutive positions, scatter-transpose.
    for (int v = t; v < NC * 4; v += 256) {
        const int c  = v >> 2;
        const int pq = v & 3;
        const float4 f = *reinterpret_cast<const float4*>(in_plane + c * NPOS + pq * 4);
        const int pb = pq * 4;
        lds[(pb + 0) * NC + c] = f.x;
        lds[(pb + 1) * NC + c] = f.y;
        lds[(pb + 2) * NC + c] = f.z;
        lds[(pb + 3) * NC + c] = f.w;
    }
    __syncthreads();

    // ---- store phase: contiguous output, ds_read_b128 from LDS ----
    float* out_block = out + (size_t)plane * (NPOS * NC) + (size_t)pos0 * NC;
    const float aw = c_aw[a];
    const float ah = c_ah[a];

    for (int v = t; v < TILE_ELEMS / 4; v += 256) {
        const int e0 = v * 4;
        const float4 f = *reinterpret_cast<const float4*>(&lds[e0]);
        float xin[4] = {f.x, f.y, f.z, f.w};
        float res[4];
        int p = e0 / NC;
        int c = e0 - p * NC;
        #pragma unroll
        for (int k = 0; k < 4; ++k) {
            const float x = xin[k];
            float r;
            if (c >= 4) {                       // conf + 80 classes: sigmoid
                r = fast_sigmoid(x);
            } else if (c == 2) {                // box w
                r = __expf(x) * aw;
            } else if (c == 3) {                // box h
                r = __expf(x) * ah;
            } else {                            // box x / y
                const int pos = pos0 + p;
                const int gy  = pos / NG;
                const int gx  = pos - gy * NG;
                const float g = (c == 0) ? (float)gx : (float)gy;
                r = (fast_sigmoid(x) + g) * STRIDE_F;
            }
            res[k] = r;
            if (++c == NC) { c = 0; ++p; }
        }
        float4 o;
        o.x = res[0]; o.y = res[1]; o.z = res[2]; o.w = res[3];
        *reinterpret_cast<float4*>(out_block + e0) = o;
    }
}

extern "C" void kernel_launch(void* const* d_in, const int* in_sizes, int n_in,
                              void* d_out, int out_size, void* d_ws, size_t ws_size,
                              hipStream_t stream) {
    const float* x = (const float*)d_in[0];
    float* out     = (float*)d_out;
    const int nB     = in_sizes[0] / (NA * NC * NPOS);   // 16
    const int blocks = nB * NA * TILES_PER_PLANE;        // 17328
    det_kernel<<<blocks, 256, 0, stream>>>(x, out);
}